// Round 3
// baseline (300.203 us; speedup 1.0000x reference)
//
#include <hip/hip_runtime.h>
#include <hip/hip_bf16.h>
#include <stdint.h>

#define B_ 2
#define N_ 2048
#define D_ 1024
#define H_ 16
#define MM 4096
#define NN 1024
#define KK 1024

typedef __bf16 bf16;
typedef __bf16 bf16x8 __attribute__((ext_vector_type(8)));
typedef float f32x4 __attribute__((ext_vector_type(4)));

struct __align__(8) bf4 { bf16 v[4]; };

// attn LDS row stride: 64 bf16 + 8 pad = 144 B
#define LDS_STRIDE 144

#define GLDS(gp, lp)                                                     \
    __builtin_amdgcn_global_load_lds(                                    \
        (const __attribute__((address_space(1))) void*)(gp),             \
        (__attribute__((address_space(3))) void*)(lp), 16, 0, 0)

// ---------------------------------------------------------------- conversions
__global__ __launch_bounds__(256) void k_cvt3(const float* __restrict__ q,
                                              const float* __restrict__ k,
                                              const float* __restrict__ v,
                                              bf16* __restrict__ qb,
                                              bf16* __restrict__ kb,
                                              bf16* __restrict__ vb) {
    const int z = blockIdx.y;
    const float* s = z == 0 ? q : z == 1 ? k : v;
    bf16* d = z == 0 ? qb : z == 1 ? kb : vb;
    size_t i = ((size_t)blockIdx.x * 256 + threadIdx.x) * 8;
    f32x4 a = *(const f32x4*)(s + i);
    f32x4 b = *(const f32x4*)(s + i + 4);
    bf16x8 o;
#pragma unroll
    for (int j = 0; j < 4; ++j) { o[j] = (bf16)a[j]; o[4 + j] = (bf16)b[j]; }
    *(bf16x8*)(d + i) = o;
}

// Wt[n][k] = (bf16)W[k][n]  (1024x1024)
__global__ void k_wtt(const float* __restrict__ W, bf16* __restrict__ Wt) {
    __shared__ float t[32][33];
    int bx = blockIdx.x * 32, by = blockIdx.y * 32;
    int tx = threadIdx.x, ty = threadIdx.y;
#pragma unroll
    for (int j = 0; j < 32; j += 8)
        t[ty + j][tx] = W[(size_t)(by + ty + j) * 1024 + bx + tx];
    __syncthreads();
#pragma unroll
    for (int j = 0; j < 32; j += 8)
        Wt[(size_t)(bx + ty + j) * 1024 + by + tx] = (bf16)t[tx][ty + j];
}

// ---------------------------------------------------------------- mask bits
__global__ __launch_bounds__(256) void k_bits(const int* __restrict__ mask,
                                              uint32_t* __restrict__ bits) {
    size_t flat = (size_t)blockIdx.x * 256 + threadIdx.x;
    int col = (int)(flat & (N_ - 1));
    int row = (int)((flat >> 11) & (N_ - 1));
    bool ok = (mask[flat] != 0) && (col <= row);
    unsigned long long bal = __ballot(ok);
    if ((threadIdx.x & 63) == 0)
        *(unsigned long long*)(bits + (flat >> 5)) = bal;
}

// ---------------------------------------------------------------- GEMM core
// C = A @ Bt^T, 128x128 tile, BK=64, 4 waves (2x2), global_load_lds w=16,
// linear LDS [128][64] (m97 structure).
__device__ __forceinline__ void mm_core(const bf16* __restrict__ A,
                                        const bf16* __restrict__ Bt,
                                        int bm0, int bn0,
                                        bf16* As, bf16* Bs,
                                        f32x4 (&acc)[4][4]) {
    const int tid = threadIdx.x, w = tid >> 6, lane = tid & 63;
    const int g = lane >> 4, li = lane & 15;
    const int wr = w >> 1, wc = w & 1;
    const int row = tid >> 3, cc = tid & 7;  // chunk c: row + 32*c

    f32x4 zz = {0.f, 0.f, 0.f, 0.f};
#pragma unroll
    for (int mf = 0; mf < 4; ++mf)
#pragma unroll
        for (int nf = 0; nf < 4; ++nf) acc[mf][nf] = zz;

    auto stage = [&](int k0) {
        // 128 rows x 8 chunks(16B) = 1024 chunks; 4 calls x 256 threads
#pragma unroll
        for (int c = 0; c < 4; ++c) {
            int ch = c * 256 + tid;
            int r = ch >> 3, cl = ch & 7;
            GLDS(A + (size_t)(bm0 + r) * KK + k0 + cl * 8,
                 As + ((size_t)c * 256 + w * 64) * 8);
        }
#pragma unroll
        for (int c = 0; c < 4; ++c) {
            int ch = c * 256 + tid;
            int r = ch >> 3, cl = ch & 7;
            GLDS(Bt + (size_t)(bn0 + r) * KK + k0 + cl * 8,
                 Bs + ((size_t)c * 256 + w * 64) * 8);
        }
    };
    (void)row; (void)cc;

    stage(0);
    for (int s = 0; s < KK / 64; ++s) {
        __syncthreads();  // drains vmcnt -> staged tile visible
#pragma unroll
        for (int kk = 0; kk < 2; ++kk) {
            bf16x8 af[4], bfr[4];
#pragma unroll
            for (int i = 0; i < 4; ++i) {
                af[i] = *(const bf16x8*)(As + (wr * 64 + i * 16 + li) * 64 + kk * 32 + g * 8);
                bfr[i] = *(const bf16x8*)(Bs + (wc * 64 + i * 16 + li) * 64 + kk * 32 + g * 8);
            }
#pragma unroll
            for (int mf = 0; mf < 4; ++mf)
#pragma unroll
                for (int nf = 0; nf < 4; ++nf)
                    acc[mf][nf] = __builtin_amdgcn_mfma_f32_16x16x32_bf16(
                        af[mf], bfr[nf], acc[mf][nf], 0, 0, 0);
        }
        __syncthreads();  // all reads done before restaging
        if (s + 1 < KK / 64) stage((s + 1) * 64);
    }
}

// fused Q/K/V projections: z = blockIdx.y picks input/weight/epilogue
__global__ __launch_bounds__(256) void k_proj(const bf16* __restrict__ qb,
                                              const bf16* __restrict__ kb,
                                              const bf16* __restrict__ vb,
                                              const bf16* __restrict__ WqT,
                                              const bf16* __restrict__ WkT,
                                              const bf16* __restrict__ WvT,
                                              bf16* __restrict__ Qh,
                                              bf16* __restrict__ Kh,
                                              bf16* __restrict__ Vt) {
    __shared__ __align__(16) bf16 As[128 * 64];
    __shared__ __align__(16) bf16 Bs[128 * 64];
    const int z = blockIdx.y;
    const bf16* A = z == 0 ? qb : z == 1 ? kb : vb;
    const bf16* Bt = z == 0 ? WqT : z == 1 ? WkT : WvT;
    int bid = blockIdx.x;
    int swz = (bid & 7) * 32 + (bid >> 3);          // 256 % 8 == 0: bijective
    int bm0 = (swz >> 3) * 128, bn0 = (swz & 7) * 128;

    f32x4 acc[4][4];
    mm_core(A, Bt, bm0, bn0, As, Bs, acc);

    const int tid = threadIdx.x, w = tid >> 6, lane = tid & 63;
    const int g = lane >> 4, li = lane & 15;
    const int wr = w >> 1, wc = w & 1;
    const float scale = (z == 0) ? 0.125f : 1.0f;

    if (z < 2) {
        bf16* C = (z == 0) ? Qh : Kh;
#pragma unroll
        for (int mf = 0; mf < 4; ++mf)
#pragma unroll
            for (int nf = 0; nf < 4; ++nf) {
                int m0 = bm0 + wr * 64 + mf * 16 + g * 4;
                int n = bn0 + wc * 64 + nf * 16 + li;
#pragma unroll
                for (int r = 0; r < 4; ++r)
                    C[(size_t)(m0 + r) * NN + n] = (bf16)(acc[mf][nf][r] * scale);
            }
    } else {
#pragma unroll
        for (int mf = 0; mf < 4; ++mf)
#pragma unroll
            for (int nf = 0; nf < 4; ++nf) {
                int m0 = bm0 + wr * 64 + mf * 16 + g * 4;
                int n = bn0 + wc * 64 + nf * 16 + li;
                int bq = m0 >> 11, tok = m0 & (N_ - 1);
                int hh = n >> 6, dv = n & 63;
                bf4 val;
#pragma unroll
                for (int r = 0; r < 4; ++r) val.v[r] = (bf16)acc[mf][nf][r];
                *(bf4*)(Vt + ((size_t)((bq * H_ + hh) * 64 + dv)) * N_ + tok) = val;
            }
    }
}

// output GEMM: out = Ob @ WoT^T + resid
__global__ __launch_bounds__(256) void k_out(const bf16* __restrict__ Ob,
                                             const bf16* __restrict__ WoT,
                                             float* __restrict__ outp,
                                             const float* __restrict__ resid) {
    __shared__ __align__(16) bf16 As[128 * 64];
    __shared__ __align__(16) bf16 Bs[128 * 64];
    int bid = blockIdx.x;
    int swz = (bid & 7) * 32 + (bid >> 3);
    int bm0 = (swz >> 3) * 128, bn0 = (swz & 7) * 128;

    f32x4 acc[4][4];
    mm_core(Ob, WoT, bm0, bn0, As, Bs, acc);

    const int tid = threadIdx.x, w = tid >> 6, lane = tid & 63;
    const int g = lane >> 4, li = lane & 15;
    const int wr = w >> 1, wc = w & 1;
#pragma unroll
    for (int mf = 0; mf < 4; ++mf)
#pragma unroll
        for (int nf = 0; nf < 4; ++nf) {
            int m0 = bm0 + wr * 64 + mf * 16 + g * 4;
            int n = bn0 + wc * 64 + nf * 16 + li;
#pragma unroll
            for (int r = 0; r < 4; ++r) {
                size_t ix = (size_t)(m0 + r) * NN + n;
                outp[ix] = acc[mf][nf][r] + resid[ix];
            }
        }
}

// ---------------------------------------------------------------- attention
// Block = (pair p, h, b): qt = p and 31-p (66 tile-rounds, perfectly flat).
// Swapped QK^T; double-buffered K/V in LDS -> 1 barrier per tile.
__global__ __launch_bounds__(256) void k_attn(const bf16* __restrict__ Qh,
                                              const bf16* __restrict__ Kh,
                                              const bf16* __restrict__ Vt,
                                              const uint32_t* __restrict__ bits,
                                              float* __restrict__ attnp,
                                              bf16* __restrict__ Ob) {
    __shared__ __align__(16) char Qs[64 * LDS_STRIDE];
    __shared__ __align__(16) char Ks[2][64 * LDS_STRIDE];
    __shared__ __align__(16) char Vs[2][64 * LDS_STRIDE];
    __shared__ __align__(16) char Ps[64 * LDS_STRIDE];
    const int tid = threadIdx.x, lane = tid & 63, w = tid >> 6;
    const int g = lane >> 4, li = lane & 15;
    const int p = blockIdx.x, h = blockIdx.y, b = blockIdx.z;
    const int srow = tid >> 3, sc = tid & 7;
    const int myrow = w * 16 + li;

    const size_t kbase = ((size_t)b * N_) * D_ + h * 64;
    const size_t vbase = ((size_t)(b * H_ + h) * 64) * N_;
    f32x4 zz = {0.f, 0.f, 0.f, 0.f};

    bf16x8 ka, kb2, va, vb2;
    auto loadK = [&](int jt) {
        const char* ks = (const char*)Kh +
            (kbase + (size_t)(jt * 64 + srow) * D_ + sc * 8) * 2;
        ka = *(const bf16x8*)ks;
        kb2 = *(const bf16x8*)(ks + (size_t)32 * D_ * 2);
    };
    auto loadV = [&](int jt) {
        const char* vs = (const char*)Vt +
            (vbase + (size_t)srow * N_ + jt * 64 + sc * 8) * 2;
        va = *(const bf16x8*)vs;
        vb2 = *(const bf16x8*)(vs + (size_t)32 * N_ * 2);
    };
    auto writeK = [&](int bi) {
        *(bf16x8*)(Ks[bi] + srow * LDS_STRIDE + sc * 16) = ka;
        *(bf16x8*)(Ks[bi] + (srow + 32) * LDS_STRIDE + sc * 16) = kb2;
    };
    auto writeV = [&](int bi) {
        *(bf16x8*)(Vs[bi] + srow * LDS_STRIDE + sc * 16) = va;
        *(bf16x8*)(Vs[bi] + (srow + 32) * LDS_STRIDE + sc * 16) = vb2;
    };

    for (int half = 0; half < 2; ++half) {
        const int qt = half ? (31 - p) : p;
        const int i0 = qt << 6;
        const size_t abase = (((size_t)b * H_ + h) * N_ + i0) * (size_t)N_;

        __syncthreads();  // previous half/pass LDS reads done
        {  // stage Q
            const char* qsrc = (const char*)Qh +
                (kbase + (size_t)(i0 + srow) * D_ + sc * 8) * 2;
            bf16x8 t0 = *(const bf16x8*)qsrc;
            bf16x8 t1 = *(const bf16x8*)(qsrc + (size_t)32 * D_ * 2);
            *(bf16x8*)(Qs + srow * LDS_STRIDE + sc * 16) = t0;
            *(bf16x8*)(Qs + (srow + 32) * LDS_STRIDE + sc * 16) = t1;
        }
        const uint32_t* mrow = bits + (((size_t)b * N_ + i0 + myrow) << 6);

        // ================= pass A: row stats =================
        float m = -1e30f, l = 0.f;
        loadK(0);
        writeK(0);
        for (int jt = 0; jt <= qt; ++jt) {
            if (jt < qt) loadK(jt + 1);
            uint2 mw = *(const uint2*)(mrow + (jt << 1));
            __syncthreads();
            const char* Kb = Ks[jt & 1];

            f32x4 s[4];
#pragma unroll
            for (int mf = 0; mf < 4; ++mf) s[mf] = zz;
#pragma unroll
            for (int kk = 0; kk < 2; ++kk) {
                const int kb = kk * 64 + (g << 4);
                bf16x8 qf = *(const bf16x8*)(Qs + myrow * LDS_STRIDE + kb);
#pragma unroll
                for (int mf = 0; mf < 4; ++mf) {
                    bf16x8 kf = *(const bf16x8*)(Kb + (mf * 16 + li) * LDS_STRIDE + kb);
                    s[mf] = __builtin_amdgcn_mfma_f32_16x16x32_bf16(kf, qf, s[mf], 0, 0, 0);
                }
            }
            if (jt < qt) writeK((jt + 1) & 1);

            float tmax = m;
#pragma unroll
            for (int mf = 0; mf < 4; ++mf) {
                uint32_t wsel = (mf < 2) ? mw.x : mw.y;
#pragma unroll
                for (int r = 0; r < 4; ++r) {
                    int sh = (mf & 1) * 16 + g * 4 + r;
                    float xv = ((wsel >> sh) & 1) ? s[mf][r] : -1e9f;
                    s[mf][r] = xv;
                    tmax = fmaxf(tmax, xv);
                }
            }
            tmax = fmaxf(tmax, __shfl_xor(tmax, 16));
            tmax = fmaxf(tmax, __shfl_xor(tmax, 32));
            float ps = 0.f;
#pragma unroll
            for (int mf = 0; mf < 4; ++mf)
#pragma unroll
                for (int r = 0; r < 4; ++r) ps += __expf(s[mf][r] - tmax);
            ps += __shfl_xor(ps, 16);
            ps += __shfl_xor(ps, 32);
            l = l * __expf(m - tmax) + ps;
            m = tmax;
        }
        const float linv = 1.0f / l;

        // ================= pass B: P + O =================
        f32x4 oacc[4];
#pragma unroll
        for (int nf = 0; nf < 4; ++nf) oacc[nf] = zz;

        __syncthreads();  // pass A reads done before restaging buf0
        loadK(0);
        loadV(0);
        writeK(0);
        writeV(0);
        for (int jt = 0; jt <= qt; ++jt) {
            if (jt < qt) { loadK(jt + 1); loadV(jt + 1); }
            uint2 mw = *(const uint2*)(mrow + (jt << 1));
            __syncthreads();
            const char* Kb = Ks[jt & 1];
            const char* Vb = Vs[jt & 1];

            f32x4 s[4];
#pragma unroll
            for (int mf = 0; mf < 4; ++mf) s[mf] = zz;
#pragma unroll
            for (int kk = 0; kk < 2; ++kk) {
                const int kb = kk * 64 + (g << 4);
                bf16x8 qf = *(const bf16x8*)(Qs + myrow * LDS_STRIDE + kb);
#pragma unroll
                for (int mf = 0; mf < 4; ++mf) {
                    bf16x8 kf = *(const bf16x8*)(Kb + (mf * 16 + li) * LDS_STRIDE + kb);
                    s[mf] = __builtin_amdgcn_mfma_f32_16x16x32_bf16(kf, qf, s[mf], 0, 0, 0);
                }
            }
            if (jt < qt) { writeK((jt + 1) & 1); writeV((jt + 1) & 1); }

#pragma unroll
            for (int mf = 0; mf < 4; ++mf) {
                uint32_t wsel = (mf < 2) ? mw.x : mw.y;
#pragma unroll
                for (int r = 0; r < 4; ++r) {
                    int sh = (mf & 1) * 16 + g * 4 + r;
                    float xv = ((wsel >> sh) & 1) ? s[mf][r] : -1e9f;
                    s[mf][r] = __expf(xv - m) * linv;
                }
                __builtin_nontemporal_store(s[mf],
                    (f32x4*)(attnp + abase + (size_t)myrow * N_ + (jt << 6) + mf * 16 + g * 4));
                bf4 pk;
#pragma unroll
                for (int r = 0; r < 4; ++r) pk.v[r] = (bf16)s[mf][r];
                *(bf4*)(Ps + myrow * LDS_STRIDE + (mf * 16 + g * 4) * 2) = pk;
            }
            // PV (Ps rows written/read by same wave)
#pragma unroll
            for (int kk = 0; kk < 2; ++kk) {
                const int kb = kk * 64 + (g << 4);
                bf16x8 pf = *(const bf16x8*)(Ps + myrow * LDS_STRIDE + kb);
#pragma unroll
                for (int nf = 0; nf < 4; ++nf) {
                    bf16x8 vf = *(const bf16x8*)(Vb + (nf * 16 + li) * LDS_STRIDE + kb);
                    oacc[nf] = __builtin_amdgcn_mfma_f32_16x16x32_bf16(pf, vf, oacc[nf], 0, 0, 0);
                }
            }
        }
        // O store
#pragma unroll
        for (int nf = 0; nf < 4; ++nf)
#pragma unroll
            for (int r = 0; r < 4; ++r) {
                int gi = i0 + w * 16 + g * 4 + r;
                Ob[((size_t)(b * N_ + gi)) * D_ + h * 64 + nf * 16 + li] = (bf16)oacc[nf][r];
            }
        // zero-fill strictly-upper tiles
        int zc0 = i0 + 64;
        if (zc0 < N_) {
            int r = tid >> 2, tc = tid & 3;
            f32x4 z = zz;
            for (int c = zc0 + tc * 4; c < N_; c += 16)
                __builtin_nontemporal_store(z, (f32x4*)(attnp + abase + (size_t)r * N_ + c));
        }
    }
}

// ---------------------------------------------------------------- layernorm
__global__ __launch_bounds__(256) void k_ln(float* __restrict__ out,
                                            const float* __restrict__ gamma,
                                            const float* __restrict__ beta) {
    const int row = blockIdx.x, t = threadIdx.x, lane = t & 63, w = t >> 6;
    float* p = out + (size_t)row * D_;
    f32x4 x = *(const f32x4*)(p + t * 4);
    float s = x[0] + x[1] + x[2] + x[3];
    float s2 = x[0] * x[0] + x[1] * x[1] + x[2] * x[2] + x[3] * x[3];
#pragma unroll
    for (int o = 1; o < 64; o <<= 1) {
        s += __shfl_xor(s, o);
        s2 += __shfl_xor(s2, o);
    }
    __shared__ float r1[4], r2[4];
    if (lane == 0) { r1[w] = s; r2[w] = s2; }
    __syncthreads();
    s = r1[0] + r1[1] + r1[2] + r1[3];
    s2 = r2[0] + r2[1] + r2[2] + r2[3];
    float mean = s * (1.f / D_);
    float var = s2 * (1.f / D_) - mean * mean;
    float rstd = rsqrtf(var + 1e-6f);
    f32x4 gv = *(const f32x4*)(gamma + t * 4);
    f32x4 bv = *(const f32x4*)(beta + t * 4);
    f32x4 y;
#pragma unroll
    for (int c = 0; c < 4; ++c) y[c] = (x[c] - mean) * rstd * gv[c] + bv[c];
    *(f32x4*)(p + t * 4) = y;
}

// ---------------------------------------------------------------- launch
extern "C" void kernel_launch(void* const* d_in, const int* in_sizes, int n_in,
                              void* d_out, int out_size, void* d_ws,
                              size_t ws_size, hipStream_t stream) {
    (void)in_sizes; (void)n_in; (void)out_size; (void)ws_size;
    const float* q = (const float*)d_in[0];
    const float* k = (const float*)d_in[1];
    const float* v = (const float*)d_in[2];
    const int* msk = (const int*)d_in[3];
    const float* Wq = (const float*)d_in[4];
    const float* Wk = (const float*)d_in[5];
    const float* Wv = (const float*)d_in[6];
    const float* Wo = (const float*)d_in[7];
    const float* gamma = (const float*)d_in[8];
    const float* beta = (const float*)d_in[9];

    float* outp = (float*)d_out;
    float* attnp = outp + (size_t)B_ * N_ * D_;

    const size_t U = (size_t)B_ * N_ * D_;   // 4,194,304
    const size_t W1 = (size_t)D_ * D_;       // 1,048,576
    bf16* ws = (bf16*)d_ws;
    bf16* qb = ws;   ws += U;
    bf16* kb = ws;   ws += U;
    bf16* vb = ws;   ws += U;
    bf16* WqT = ws;  ws += W1;
    bf16* WkT = ws;  ws += W1;
    bf16* WvT = ws;  ws += W1;
    bf16* WoT = ws;  ws += W1;
    bf16* Qh = ws;   ws += U;
    bf16* Kh = ws;   ws += U;
    bf16* Vt = ws;   ws += U;   // (B,H,DV,N)
    bf16* Ob = ws;   ws += U;
    uint32_t* bits = (uint32_t*)ws;  // 1 MB

    k_cvt3<<<dim3(U / 8 / 256, 3), 256, 0, stream>>>(q, k, v, qb, kb, vb);
    dim3 tb(32, 8);
    k_wtt<<<dim3(32, 32), tb, 0, stream>>>(Wq, WqT);
    k_wtt<<<dim3(32, 32), tb, 0, stream>>>(Wk, WkT);
    k_wtt<<<dim3(32, 32), tb, 0, stream>>>(Wv, WvT);
    k_wtt<<<dim3(32, 32), tb, 0, stream>>>(Wo, WoT);
    k_bits<<<(size_t)B_ * N_ * N_ / 256, 256, 0, stream>>>(msk, bits);

    k_proj<<<dim3(256, 3), 256, 0, stream>>>(qb, kb, vb, WqT, WkT, WvT, Qh, Kh, Vt);

    k_attn<<<dim3(16, H_, B_), 256, 0, stream>>>(Qh, Kh, Vt, bits, attnp, Ob);

    k_out<<<256, 256, 0, stream>>>(Ob, WoT, outp, q);

    k_ln<<<B_ * N_, 256, 0, stream>>>(outp, gamma, beta);
}